// Round 2
// baseline (280.216 us; speedup 1.0000x reference)
//
#include <hip/hip_runtime.h>

#define HID 512
#define HEADS 8
#define HD 64
#define BATCH 2
#define SEQ 384
#define MROWS (BATCH * SEQ)  // 768

// 2*log2(e): Eq = exp2(C1 * qW) == exp(2*qW)
#define C1 2.8853900817779268f
// log2(e)/8: softmax exponent scale (energy = raw/8)
#define SSCL 0.18033688011112043f

// ---------------------------------------------------------------------------
// prep: fold Ww/Wu into Wq/Wk (per-head block-diagonal), fold biases, vv2=-2vv
// ---------------------------------------------------------------------------
__global__ __launch_bounds__(256) void prep_kernel(
    const float* __restrict__ Wq, const float* __restrict__ bq,
    const float* __restrict__ Wk, const float* __restrict__ bk,
    const float* __restrict__ Ww, const float* __restrict__ bw,
    const float* __restrict__ Wu, const float* __restrict__ bu,
    const float* __restrict__ vv,
    float* __restrict__ wqe, float* __restrict__ wke,
    float* __restrict__ bqe, float* __restrict__ bke,
    float* __restrict__ vv2)
{
    int tid = blockIdx.x * 256 + threadIdx.x;
    if (tid < 262144) {
        int i = tid >> 9, n = tid & 511, h = n >> 6, j = n & 63;
        const float* wrow = Wq + i * HID + h * HD;
        float s = 0.f;
        #pragma unroll 8
        for (int t = 0; t < 64; ++t) s = fmaf(wrow[t], Ww[t * 64 + j], s);
        wqe[tid] = s;
    } else if (tid < 524288) {
        int idx = tid - 262144;
        int i = idx >> 9, n = idx & 511, h = n >> 6, j = n & 63;
        const float* wrow = Wk + i * HID + h * HD;
        float s = 0.f;
        #pragma unroll 8
        for (int t = 0; t < 64; ++t) s = fmaf(wrow[t], Wu[t * 64 + j], s);
        wke[idx] = s;
    } else if (tid < 524800) {
        int n = tid - 524288, h = n >> 6, j = n & 63;
        float s = bw[j];
        for (int t = 0; t < 64; ++t) s = fmaf(bq[h * 64 + t], Ww[t * 64 + j], s);
        bqe[n] = s;
    } else if (tid < 525312) {
        int n = tid - 524800, h = n >> 6, j = n & 63;
        float s = bu[j];
        for (int t = 0; t < 64; ++t) s = fmaf(bk[h * 64 + t], Wu[t * 64 + j], s);
        bke[n] = s;
    } else if (tid < 525376) {
        int d = tid - 525312;
        vv2[d] = -2.0f * vv[d];
    }
}

// ---------------------------------------------------------------------------
// fp32 GEMM: [M=768,K=512] @ [512,512] + bias
// mode 0: plain   mode 1: exp2(C1*y), row-major   mode 2: exp2(C1*y), write
// transposed-packed Ek4[(b*8+h)*16 + d4][k][4]  (k = row % 384, d4 = (col&63)/4)
// tile: BM=32, BN=64, BK=32; 256 threads; 2x4 per thread
// ---------------------------------------------------------------------------
__device__ __forceinline__ void gemm_body(
    const float* __restrict__ A, const float* __restrict__ W,
    const float* __restrict__ bias, float* __restrict__ out,
    int mode, int bm, int bn)
{
    __shared__ float As[32][34];  // [k][m]
    __shared__ float Bs[32][68];  // [k][n]
    int tid = threadIdx.x;
    int tx = tid & 15, ty = tid >> 4;

    float acc[2][4];
    #pragma unroll
    for (int i = 0; i < 2; ++i)
        #pragma unroll
        for (int j = 0; j < 4; ++j) acc[i][j] = 0.f;

    for (int kt = 0; kt < 16; ++kt) {
        #pragma unroll
        for (int i = 0; i < 4; ++i) {
            int e = tid + i * 256, r = e >> 5, c = e & 31;
            As[c][r] = A[(bm * 32 + r) * HID + kt * 32 + c];
        }
        #pragma unroll
        for (int i = 0; i < 8; ++i) {
            int e = tid + i * 256, r = e >> 6, c = e & 63;
            Bs[r][c] = W[(kt * 32 + r) * HID + bn * 64 + c];
        }
        __syncthreads();
        #pragma unroll
        for (int kk = 0; kk < 32; ++kk) {
            const float2 a = *(const float2*)&As[kk][ty * 2];
            const float4 b4 = *(const float4*)&Bs[kk][tx * 4];
            acc[0][0] = fmaf(a.x, b4.x, acc[0][0]);
            acc[0][1] = fmaf(a.x, b4.y, acc[0][1]);
            acc[0][2] = fmaf(a.x, b4.z, acc[0][2]);
            acc[0][3] = fmaf(a.x, b4.w, acc[0][3]);
            acc[1][0] = fmaf(a.y, b4.x, acc[1][0]);
            acc[1][1] = fmaf(a.y, b4.y, acc[1][1]);
            acc[1][2] = fmaf(a.y, b4.z, acc[1][2]);
            acc[1][3] = fmaf(a.y, b4.w, acc[1][3]);
        }
        __syncthreads();
    }

    int ncol = bn * 64 + tx * 4;
    float4 bias4 = *(const float4*)&bias[ncol];
    #pragma unroll
    for (int i = 0; i < 2; ++i) {
        int m = bm * 32 + ty * 2 + i;
        float4 o;
        o.x = acc[i][0] + bias4.x;
        o.y = acc[i][1] + bias4.y;
        o.z = acc[i][2] + bias4.z;
        o.w = acc[i][3] + bias4.w;
        if (mode != 0) {
            o.x = __builtin_amdgcn_exp2f(C1 * o.x);
            o.y = __builtin_amdgcn_exp2f(C1 * o.y);
            o.z = __builtin_amdgcn_exp2f(C1 * o.z);
            o.w = __builtin_amdgcn_exp2f(C1 * o.w);
        }
        if (mode == 2) {
            int bb = m / SEQ, k = m - bb * SEQ;
            int hh = ncol >> 6, d4 = (ncol & 63) >> 2;
            *(float4*)&out[(((size_t)(bb * 8 + hh) * 16 + d4) * SEQ + k) << 2] = o;
        } else {
            *(float4*)&out[(size_t)m * HID + ncol] = o;
        }
    }
}

__global__ __launch_bounds__(256) void proj3_kernel(
    const float* __restrict__ q, const float* __restrict__ k, const float* __restrict__ v,
    const float* __restrict__ wqe, const float* __restrict__ wke, const float* __restrict__ Wv,
    const float* __restrict__ bqe, const float* __restrict__ bke, const float* __restrict__ bv,
    float* __restrict__ Eq, float* __restrict__ Ek4, float* __restrict__ V)
{
    int p = blockIdx.z;
    const float* A = (p == 0) ? q : ((p == 1) ? k : v);
    const float* W = (p == 0) ? wqe : ((p == 1) ? wke : Wv);
    const float* bias = (p == 0) ? bqe : ((p == 1) ? bke : bv);
    float* out = (p == 0) ? Eq : ((p == 1) ? Ek4 : V);
    int mode = (p == 2) ? 0 : ((p == 0) ? 1 : 2);
    gemm_body(A, W, bias, out, mode, blockIdx.x, blockIdx.y);
}

__global__ __launch_bounds__(256) void gemm_kernel(
    const float* __restrict__ A, const float* __restrict__ W,
    const float* __restrict__ bias, float* __restrict__ out)
{
    gemm_body(A, W, bias, out, 0, blockIdx.x, blockIdx.y);
}

// ---------------------------------------------------------------------------
// attention: energy (Eq*Ek + rcp) -> softmax -> write attn -> attn@V
// grid (48, 16): x = q-block of 8 rows, y = b*8+h. 256 thr = 4 waves, 2 q/wave.
// Ek4 layout: [(b*8+h)*16 + d4][k][4] -> float4 load per (d4, k=lane) coalesced
// ---------------------------------------------------------------------------
__global__ __launch_bounds__(256) void attn_kernel(
    const float* __restrict__ Eq, const float* __restrict__ Ek4,
    const float* __restrict__ V, const float* __restrict__ vv2,
    float* __restrict__ attnOut, float* __restrict__ X)
{
    __shared__ float4 EqL[8][16];   // [q][d4]
    __shared__ float4 vvL[16];      // vv2 packed
    __shared__ float2 aP[4][SEQ];   // per-wave attn rows {a_q0, a_q1}

    int bh = blockIdx.y;
    int b = bh >> 3, h = bh & 7;
    int qbase = blockIdx.x * 8;
    int tid = threadIdx.x, wave = tid >> 6, lane = tid & 63;

    if (tid < 128) {
        int qq = tid >> 4, d4 = tid & 15;
        EqL[qq][d4] = *(const float4*)&Eq[(size_t)(b * SEQ + qbase + qq) * HID + h * HD + d4 * 4];
    } else if (tid < 144) {
        vvL[tid - 128] = *(const float4*)&vv2[(tid - 128) * 4];
    }
    __syncthreads();

    int q0 = wave * 2, q1 = q0 + 1;
    float e0[6], e1[6];
    const float4* ekbase = (const float4*)Ek4 + (size_t)bh * 16 * SEQ;

    #pragma unroll
    for (int kt = 0; kt < 6; ++kt) {
        const float4* ekp = ekbase + kt * 64 + lane;
        float r0 = 0.f, r1 = 0.f;
        #pragma unroll
        for (int d4 = 0; d4 < 16; ++d4) {
            float4 ek = ekp[d4 * SEQ];
            float4 g0 = EqL[q0][d4];
            float4 g1 = EqL[q1][d4];
            float4 w  = vvL[d4];
            r0 = fmaf(w.x, __builtin_amdgcn_rcpf(fmaf(g0.x, ek.x, 1.f)), r0);
            r0 = fmaf(w.y, __builtin_amdgcn_rcpf(fmaf(g0.y, ek.y, 1.f)), r0);
            r0 = fmaf(w.z, __builtin_amdgcn_rcpf(fmaf(g0.z, ek.z, 1.f)), r0);
            r0 = fmaf(w.w, __builtin_amdgcn_rcpf(fmaf(g0.w, ek.w, 1.f)), r0);
            r1 = fmaf(w.x, __builtin_amdgcn_rcpf(fmaf(g1.x, ek.x, 1.f)), r1);
            r1 = fmaf(w.y, __builtin_amdgcn_rcpf(fmaf(g1.y, ek.y, 1.f)), r1);
            r1 = fmaf(w.z, __builtin_amdgcn_rcpf(fmaf(g1.z, ek.z, 1.f)), r1);
            r1 = fmaf(w.w, __builtin_amdgcn_rcpf(fmaf(g1.w, ek.w, 1.f)), r1);
        }
        e0[kt] = r0; e1[kt] = r1;
    }

    // softmax over k (384 = 6 tiles x 64 lanes), scale 1/8 folded into exp2
    float m0 = e0[0], m1 = e1[0];
    #pragma unroll
    for (int t = 1; t < 6; ++t) { m0 = fmaxf(m0, e0[t]); m1 = fmaxf(m1, e1[t]); }
    #pragma unroll
    for (int off = 1; off < 64; off <<= 1) {
        m0 = fmaxf(m0, __shfl_xor(m0, off));
        m1 = fmaxf(m1, __shfl_xor(m1, off));
    }
    float a0[6], a1[6], s0 = 0.f, s1 = 0.f;
    #pragma unroll
    for (int t = 0; t < 6; ++t) {
        a0[t] = __builtin_amdgcn_exp2f((e0[t] - m0) * SSCL); s0 += a0[t];
        a1[t] = __builtin_amdgcn_exp2f((e1[t] - m1) * SSCL); s1 += a1[t];
    }
    #pragma unroll
    for (int off = 1; off < 64; off <<= 1) {
        s0 += __shfl_xor(s0, off);
        s1 += __shfl_xor(s1, off);
    }
    float z0 = __builtin_amdgcn_rcpf(s0), z1 = __builtin_amdgcn_rcpf(s1);

    size_t abase = (size_t)bh * SEQ * SEQ;
    #pragma unroll
    for (int t = 0; t < 6; ++t) {
        float v0 = a0[t] * z0, v1 = a1[t] * z1;
        attnOut[abase + (size_t)(qbase + q0) * SEQ + t * 64 + lane] = v0;
        attnOut[abase + (size_t)(qbase + q1) * SEQ + t * 64 + lane] = v1;
        aP[wave][t * 64 + lane] = make_float2(v0, v1);
    }
    // no barrier: aP[wave] is written and read by the same wave

    // attn @ V: lane = ko*16 + d4p; each lane does 4 d's, k strided by 4
    int ko = lane >> 4, d4p = lane & 15;
    const float4* vb = (const float4*)&V[(size_t)b * SEQ * HID + h * HD + d4p * 4];
    float4 x0 = make_float4(0.f, 0.f, 0.f, 0.f);
    float4 x1 = make_float4(0.f, 0.f, 0.f, 0.f);
    #pragma unroll 4
    for (int k = ko; k < SEQ; k += 4) {
        float4 v = vb[(size_t)k * (HID / 4)];
        float2 a = aP[wave][k];
        x0.x = fmaf(a.x, v.x, x0.x); x0.y = fmaf(a.x, v.y, x0.y);
        x0.z = fmaf(a.x, v.z, x0.z); x0.w = fmaf(a.x, v.w, x0.w);
        x1.x = fmaf(a.y, v.x, x1.x); x1.y = fmaf(a.y, v.y, x1.y);
        x1.z = fmaf(a.y, v.z, x1.z); x1.w = fmaf(a.y, v.w, x1.w);
    }
    #pragma unroll
    for (int off = 16; off < 64; off <<= 1) {
        x0.x += __shfl_xor(x0.x, off); x0.y += __shfl_xor(x0.y, off);
        x0.z += __shfl_xor(x0.z, off); x0.w += __shfl_xor(x0.w, off);
        x1.x += __shfl_xor(x1.x, off); x1.y += __shfl_xor(x1.y, off);
        x1.z += __shfl_xor(x1.z, off); x1.w += __shfl_xor(x1.w, off);
    }
    if (ko == 0) {
        *(float4*)&X[(size_t)(b * SEQ + qbase + q0) * HID + h * HD + d4p * 4] = x0;
        *(float4*)&X[(size_t)(b * SEQ + qbase + q1) * HID + h * HD + d4p * 4] = x1;
    }
}

// ---------------------------------------------------------------------------
extern "C" void kernel_launch(void* const* d_in, const int* in_sizes, int n_in,
                              void* d_out, int out_size, void* d_ws, size_t ws_size,
                              hipStream_t stream)
{
    const float* query = (const float*)d_in[0];
    const float* key   = (const float*)d_in[1];
    const float* value = (const float*)d_in[2];
    const float* Wq = (const float*)d_in[3];
    const float* bq = (const float*)d_in[4];
    const float* Wk = (const float*)d_in[5];
    const float* bk = (const float*)d_in[6];
    const float* Wv = (const float*)d_in[7];
    const float* bv = (const float*)d_in[8];
    const float* Ww = (const float*)d_in[9];
    const float* bw = (const float*)d_in[10];
    const float* Wu = (const float*)d_in[11];
    const float* bu = (const float*)d_in[12];
    const float* vv = (const float*)d_in[13];
    const float* Wo = (const float*)d_in[14];
    const float* bo = (const float*)d_in[15];

    float* out_x    = (float*)d_out;                 // [2,384,512]
    float* out_attn = out_x + (size_t)MROWS * HID;   // [2,8,384,384]

    float* ws  = (float*)d_ws;
    float* wqe = ws;                 // 262144
    float* wke = wqe + 262144;       // 262144
    float* bqe = wke + 262144;       // 512
    float* bke = bqe + 512;          // 512
    float* vv2 = bke + 512;          // 64
    float* EqB = vv2 + 64;           // 393216
    float* Ek4 = EqB + 393216;       // 393216 (transposed-packed)
    float* Vw  = Ek4 + 393216;       // 393216
    float* Xw  = Vw + 393216;        // 393216

    prep_kernel<<<dim3(2053), 256, 0, stream>>>(Wq, bq, Wk, bk, Ww, bw, Wu, bu, vv,
                                                wqe, wke, bqe, bke, vv2);
    proj3_kernel<<<dim3(24, 8, 3), 256, 0, stream>>>(query, key, value,
                                                     wqe, wke, Wv,
                                                     bqe, bke, bv,
                                                     EqB, Ek4, Vw);
    attn_kernel<<<dim3(48, 16), 256, 0, stream>>>(EqB, Ek4, Vw, vv2, out_attn, Xw);
    gemm_kernel<<<dim3(24, 8), 256, 0, stream>>>(Xw, Wo, bo, out_x);
}

// Round 3
// 196.549 us; speedup vs baseline: 1.4257x; 1.4257x over previous
//
#include <hip/hip_runtime.h>

#define HID 512
#define HEADS 8
#define HD 64
#define BATCH 2
#define SEQ 384
#define MROWS (BATCH * SEQ)  // 768

// 2*log2(e): Eq = exp2(C1 * qW) == exp(2*qW)
#define C1 2.8853900817779268f
// log2(e)/8: softmax exponent scale (energy = raw/8)
#define SSCL 0.18033688011112043f

// ---------------------------------------------------------------------------
// prep: fold Ww/Wu into Wq/Wk (per-head block-diagonal), fold biases, vv2=-2vv
// ---------------------------------------------------------------------------
__global__ __launch_bounds__(256) void prep_kernel(
    const float* __restrict__ Wq, const float* __restrict__ bq,
    const float* __restrict__ Wk, const float* __restrict__ bk,
    const float* __restrict__ Ww, const float* __restrict__ bw,
    const float* __restrict__ Wu, const float* __restrict__ bu,
    const float* __restrict__ vv,
    float* __restrict__ wqe, float* __restrict__ wke,
    float* __restrict__ bqe, float* __restrict__ bke,
    float* __restrict__ vv2)
{
    int tid = blockIdx.x * 256 + threadIdx.x;
    if (tid < 262144) {
        int i = tid >> 9, n = tid & 511, h = n >> 6, j = n & 63;
        const float* wrow = Wq + i * HID + h * HD;
        float s = 0.f;
        #pragma unroll 8
        for (int t = 0; t < 64; ++t) s = fmaf(wrow[t], Ww[t * 64 + j], s);
        wqe[tid] = s;
    } else if (tid < 524288) {
        int idx = tid - 262144;
        int i = idx >> 9, n = idx & 511, h = n >> 6, j = n & 63;
        const float* wrow = Wk + i * HID + h * HD;
        float s = 0.f;
        #pragma unroll 8
        for (int t = 0; t < 64; ++t) s = fmaf(wrow[t], Wu[t * 64 + j], s);
        wke[idx] = s;
    } else if (tid < 524800) {
        int n = tid - 524288, h = n >> 6, j = n & 63;
        float s = bw[j];
        for (int t = 0; t < 64; ++t) s = fmaf(bq[h * 64 + t], Ww[t * 64 + j], s);
        bqe[n] = s;
    } else if (tid < 525312) {
        int n = tid - 524800, h = n >> 6, j = n & 63;
        float s = bu[j];
        for (int t = 0; t < 64; ++t) s = fmaf(bk[h * 64 + t], Wu[t * 64 + j], s);
        bke[n] = s;
    } else if (tid < 525376) {
        int d = tid - 525312;
        vv2[d] = -2.0f * vv[d];
    }
}

// ---------------------------------------------------------------------------
// fp32 GEMM: [M=768,K=512] @ [512,512] + bias
// mode 0: plain   mode 1: exp2(C1*y), row-major   mode 2: exp2(C1*y), write
// transposed-packed Ek4[(b*8+h)*16 + d4][k][4]
// tile: BM=32, BN=64, BK=32; 256 threads; 2x4 per thread
// ---------------------------------------------------------------------------
__device__ __forceinline__ void gemm_body(
    const float* __restrict__ A, const float* __restrict__ W,
    const float* __restrict__ bias, float* __restrict__ out,
    int mode, int bm, int bn)
{
    __shared__ float As[32][34];  // [k][m]
    __shared__ float Bs[32][68];  // [k][n]
    int tid = threadIdx.x;
    int tx = tid & 15, ty = tid >> 4;

    float acc[2][4];
    #pragma unroll
    for (int i = 0; i < 2; ++i)
        #pragma unroll
        for (int j = 0; j < 4; ++j) acc[i][j] = 0.f;

    for (int kt = 0; kt < 16; ++kt) {
        #pragma unroll
        for (int i = 0; i < 4; ++i) {
            int e = tid + i * 256, r = e >> 5, c = e & 31;
            As[c][r] = A[(bm * 32 + r) * HID + kt * 32 + c];
        }
        #pragma unroll
        for (int i = 0; i < 2; ++i) {
            int e = tid * 2 + i;          // 512 float4 = 32 rows x 16 float4
            int r = e >> 4, c4 = e & 15;
            *(float4*)&Bs[r][c4 * 4] =
                *(const float4*)&W[(kt * 32 + r) * HID + bn * 64 + c4 * 4];
        }
        __syncthreads();
        #pragma unroll
        for (int kk = 0; kk < 32; ++kk) {
            const float2 a = *(const float2*)&As[kk][ty * 2];
            const float4 b4 = *(const float4*)&Bs[kk][tx * 4];
            acc[0][0] = fmaf(a.x, b4.x, acc[0][0]);
            acc[0][1] = fmaf(a.x, b4.y, acc[0][1]);
            acc[0][2] = fmaf(a.x, b4.z, acc[0][2]);
            acc[0][3] = fmaf(a.x, b4.w, acc[0][3]);
            acc[1][0] = fmaf(a.y, b4.x, acc[1][0]);
            acc[1][1] = fmaf(a.y, b4.y, acc[1][1]);
            acc[1][2] = fmaf(a.y, b4.z, acc[1][2]);
            acc[1][3] = fmaf(a.y, b4.w, acc[1][3]);
        }
        __syncthreads();
    }

    int ncol = bn * 64 + tx * 4;
    float4 bias4 = *(const float4*)&bias[ncol];
    #pragma unroll
    for (int i = 0; i < 2; ++i) {
        int m = bm * 32 + ty * 2 + i;
        float4 o;
        o.x = acc[i][0] + bias4.x;
        o.y = acc[i][1] + bias4.y;
        o.z = acc[i][2] + bias4.z;
        o.w = acc[i][3] + bias4.w;
        if (mode != 0) {
            o.x = __builtin_amdgcn_exp2f(C1 * o.x);
            o.y = __builtin_amdgcn_exp2f(C1 * o.y);
            o.z = __builtin_amdgcn_exp2f(C1 * o.z);
            o.w = __builtin_amdgcn_exp2f(C1 * o.w);
        }
        if (mode == 2) {
            int bb = m / SEQ, k = m - bb * SEQ;
            int hh = ncol >> 6, d4 = (ncol & 63) >> 2;
            *(float4*)&out[(((size_t)(bb * 8 + hh) * 16 + d4) * SEQ + k) << 2] = o;
        } else {
            *(float4*)&out[(size_t)m * HID + ncol] = o;
        }
    }
}

__global__ __launch_bounds__(256) void proj3_kernel(
    const float* __restrict__ q, const float* __restrict__ k, const float* __restrict__ v,
    const float* __restrict__ wqe, const float* __restrict__ wke, const float* __restrict__ Wv,
    const float* __restrict__ bqe, const float* __restrict__ bke, const float* __restrict__ bv,
    float* __restrict__ Eq, float* __restrict__ Ek4, float* __restrict__ V)
{
    int p = blockIdx.z;
    const float* A = (p == 0) ? q : ((p == 1) ? k : v);
    const float* W = (p == 0) ? wqe : ((p == 1) ? wke : Wv);
    const float* bias = (p == 0) ? bqe : ((p == 1) ? bke : bv);
    float* out = (p == 0) ? Eq : ((p == 1) ? Ek4 : V);
    int mode = (p == 2) ? 0 : ((p == 0) ? 1 : 2);
    gemm_body(A, W, bias, out, mode, blockIdx.x, blockIdx.y);
}

__global__ __launch_bounds__(256) void gemm_kernel(
    const float* __restrict__ A, const float* __restrict__ W,
    const float* __restrict__ bias, float* __restrict__ out)
{
    gemm_body(A, W, bias, out, 0, blockIdx.x, blockIdx.y);
}

// ---------------------------------------------------------------------------
// attention v3: 1 q-row per wave. grid (96, 16), 256 thr = 4 waves = 4 q rows.
// Eq/vv2 are wave-uniform -> scalar operands; Ek4 loads coalesced b128.
// No __syncthreads anywhere (aP is wave-private).
// ---------------------------------------------------------------------------
__global__ __launch_bounds__(256, 6) void attn_kernel(
    const float* __restrict__ Eq, const float* __restrict__ Ek4,
    const float* __restrict__ V, const float* __restrict__ vv2,
    float* __restrict__ attnOut, float* __restrict__ X)
{
    __shared__ float aP[4][SEQ];

    int bh = blockIdx.y;
    int b = bh >> 3, h = bh & 7;
    int tid = threadIdx.x;
    int wave = __builtin_amdgcn_readfirstlane(tid >> 6);
    int lane = tid & 63;
    int q = blockIdx.x * 4 + wave;

    const float* eqrow = Eq + (size_t)(b * SEQ + q) * HID + h * HD;  // uniform
    const float4* ekbase = (const float4*)Ek4 + (size_t)bh * 16 * SEQ + lane;

    float e[6];
    #pragma unroll
    for (int kt = 0; kt < 6; ++kt) e[kt] = 0.f;

    // d-chunks of 16 (4 d4-groups); keep live-set small, loads per chunk = 24
    #pragma unroll 1
    for (int c = 0; c < 4; ++c) {
        float g[16], w[16];
        #pragma unroll
        for (int j = 0; j < 16; ++j) {
            g[j] = eqrow[c * 16 + j];   // wave-uniform -> s_load
            w[j] = vv2[c * 16 + j];     // wave-uniform -> s_load
        }
        const float4* ekc = ekbase + (size_t)c * 4 * SEQ;
        #pragma unroll
        for (int kt = 0; kt < 6; ++kt) {
            const float4* ekp = ekc + kt * 64;
            float4 k0 = ekp[0 * SEQ];
            float4 k1 = ekp[1 * SEQ];
            float4 k2 = ekp[2 * SEQ];
            float4 k3 = ekp[3 * SEQ];
            float r = e[kt];
            r = fmaf(w[0],  __builtin_amdgcn_rcpf(fmaf(g[0],  k0.x, 1.f)), r);
            r = fmaf(w[1],  __builtin_amdgcn_rcpf(fmaf(g[1],  k0.y, 1.f)), r);
            r = fmaf(w[2],  __builtin_amdgcn_rcpf(fmaf(g[2],  k0.z, 1.f)), r);
            r = fmaf(w[3],  __builtin_amdgcn_rcpf(fmaf(g[3],  k0.w, 1.f)), r);
            r = fmaf(w[4],  __builtin_amdgcn_rcpf(fmaf(g[4],  k1.x, 1.f)), r);
            r = fmaf(w[5],  __builtin_amdgcn_rcpf(fmaf(g[5],  k1.y, 1.f)), r);
            r = fmaf(w[6],  __builtin_amdgcn_rcpf(fmaf(g[6],  k1.z, 1.f)), r);
            r = fmaf(w[7],  __builtin_amdgcn_rcpf(fmaf(g[7],  k1.w, 1.f)), r);
            r = fmaf(w[8],  __builtin_amdgcn_rcpf(fmaf(g[8],  k2.x, 1.f)), r);
            r = fmaf(w[9],  __builtin_amdgcn_rcpf(fmaf(g[9],  k2.y, 1.f)), r);
            r = fmaf(w[10], __builtin_amdgcn_rcpf(fmaf(g[10], k2.z, 1.f)), r);
            r = fmaf(w[11], __builtin_amdgcn_rcpf(fmaf(g[11], k2.w, 1.f)), r);
            r = fmaf(w[12], __builtin_amdgcn_rcpf(fmaf(g[12], k3.x, 1.f)), r);
            r = fmaf(w[13], __builtin_amdgcn_rcpf(fmaf(g[13], k3.y, 1.f)), r);
            r = fmaf(w[14], __builtin_amdgcn_rcpf(fmaf(g[14], k3.z, 1.f)), r);
            r = fmaf(w[15], __builtin_amdgcn_rcpf(fmaf(g[15], k3.w, 1.f)), r);
            e[kt] = r;
        }
    }

    // softmax over k for this wave's single q row
    float m = e[0];
    #pragma unroll
    for (int t = 1; t < 6; ++t) m = fmaxf(m, e[t]);
    #pragma unroll
    for (int off = 1; off < 64; off <<= 1) m = fmaxf(m, __shfl_xor(m, off));
    float a[6], s = 0.f;
    #pragma unroll
    for (int t = 0; t < 6; ++t) {
        a[t] = __builtin_amdgcn_exp2f((e[t] - m) * SSCL);
        s += a[t];
    }
    #pragma unroll
    for (int off = 1; off < 64; off <<= 1) s += __shfl_xor(s, off);
    float z = __builtin_amdgcn_rcpf(s);

    size_t abase = (size_t)bh * SEQ * SEQ + (size_t)q * SEQ;
    #pragma unroll
    for (int t = 0; t < 6; ++t) {
        float av = a[t] * z;
        attnOut[abase + t * 64 + lane] = av;
        aP[wave][t * 64 + lane] = av;
    }
    // no barrier: aP[wave] written and read by the same wave

    // attn @ V: lane = ko*16 + d4p; 4 k-phases, float4 over d
    int ko = lane >> 4, d4p = lane & 15;
    const float4* vb = (const float4*)&V[(size_t)b * SEQ * HID + h * HD + d4p * 4];
    float4 x = make_float4(0.f, 0.f, 0.f, 0.f);
    #pragma unroll 8
    for (int k = ko; k < SEQ; k += 4) {
        float4 v = vb[(size_t)k * (HID / 4)];
        float av = aP[wave][k];
        x.x = fmaf(av, v.x, x.x);
        x.y = fmaf(av, v.y, x.y);
        x.z = fmaf(av, v.z, x.z);
        x.w = fmaf(av, v.w, x.w);
    }
    #pragma unroll
    for (int off = 16; off < 64; off <<= 1) {
        x.x += __shfl_xor(x.x, off);
        x.y += __shfl_xor(x.y, off);
        x.z += __shfl_xor(x.z, off);
        x.w += __shfl_xor(x.w, off);
    }
    if (ko == 0) {
        *(float4*)&X[(size_t)(b * SEQ + q) * HID + h * HD + d4p * 4] = x;
    }
}

// ---------------------------------------------------------------------------
extern "C" void kernel_launch(void* const* d_in, const int* in_sizes, int n_in,
                              void* d_out, int out_size, void* d_ws, size_t ws_size,
                              hipStream_t stream)
{
    const float* query = (const float*)d_in[0];
    const float* key   = (const float*)d_in[1];
    const float* value = (const float*)d_in[2];
    const float* Wq = (const float*)d_in[3];
    const float* bq = (const float*)d_in[4];
    const float* Wk = (const float*)d_in[5];
    const float* bk = (const float*)d_in[6];
    const float* Wv = (const float*)d_in[7];
    const float* bv = (const float*)d_in[8];
    const float* Ww = (const float*)d_in[9];
    const float* bw = (const float*)d_in[10];
    const float* Wu = (const float*)d_in[11];
    const float* bu = (const float*)d_in[12];
    const float* vv = (const float*)d_in[13];
    const float* Wo = (const float*)d_in[14];
    const float* bo = (const float*)d_in[15];

    float* out_x    = (float*)d_out;                 // [2,384,512]
    float* out_attn = out_x + (size_t)MROWS * HID;   // [2,8,384,384]

    float* ws  = (float*)d_ws;
    float* wqe = ws;                 // 262144
    float* wke = wqe + 262144;       // 262144
    float* bqe = wke + 262144;       // 512
    float* bke = bqe + 512;          // 512
    float* vv2 = bke + 512;          // 64
    float* EqB = vv2 + 64;           // 393216
    float* Ek4 = EqB + 393216;       // 393216 (transposed-packed)
    float* Vw  = Ek4 + 393216;       // 393216
    float* Xw  = Vw + 393216;        // 393216

    prep_kernel<<<dim3(2053), 256, 0, stream>>>(Wq, bq, Wk, bk, Ww, bw, Wu, bu, vv,
                                                wqe, wke, bqe, bke, vv2);
    proj3_kernel<<<dim3(24, 8, 3), 256, 0, stream>>>(query, key, value,
                                                     wqe, wke, Wv,
                                                     bqe, bke, bv,
                                                     EqB, Ek4, Vw);
    attn_kernel<<<dim3(96, 16), 256, 0, stream>>>(EqB, Ek4, Vw, vv2, out_attn, Xw);
    gemm_kernel<<<dim3(24, 8), 256, 0, stream>>>(Xw, Wo, bo, out_x);
}